// Round 15
// baseline (2501.522 us; speedup 1.0000x reference)
//
#include <hip/hip_runtime.h>
#include <math.h>

#define S_LEN 2048
#define EMB 1024
#define NHEAD 16
#define HDIM 64
#define NLAYER 6
#define VOCAB 32000
#define FFDIM 4096

using f32x4 = __attribute__((ext_vector_type(4))) float;
using bf16x8 = __attribute__((ext_vector_type(8))) __bf16;
typedef unsigned short us;

static __device__ __forceinline__ unsigned short f2bf(float f) {
  union { float f; unsigned int u; } v; v.f = f;
  unsigned int r = v.u + 0x7FFFu + ((v.u >> 16) & 1u);
  return (unsigned short)(r >> 16);
}

#define GLOAD_LDS16(g, l)                                                      \
  __builtin_amdgcn_global_load_lds(                                            \
      (const __attribute__((address_space(1))) void*)(g),                      \
      (__attribute__((address_space(3))) void*)(l), 16, 0, 0)

// ---------------- f32 -> bf16 bulk convert ----------------
__global__ __launch_bounds__(256) void cvt_bf16_kernel(
    const float* __restrict__ in, us* __restrict__ out, long n) {
  long i = ((long)blockIdx.x * 256 + threadIdx.x) * 8;
  if (i >= n) return;
  const float4* p = (const float4*)(in + i);
  float4 a = p[0], b = p[1];
  uint4 o;
  o.x = (unsigned)f2bf(a.x) | ((unsigned)f2bf(a.y) << 16);
  o.y = (unsigned)f2bf(a.z) | ((unsigned)f2bf(a.w) << 16);
  o.z = (unsigned)f2bf(b.x) | ((unsigned)f2bf(b.y) << 16);
  o.w = (unsigned)f2bf(b.z) | ((unsigned)f2bf(b.w) << 16);
  *(uint4*)(out + i) = o;
}

// ---------------- embedding ----------------
__global__ __launch_bounds__(256) void embed_kernel(
    const int* __restrict__ tok, const float* __restrict__ Wemb,
    const float* __restrict__ Wpos, float* __restrict__ x) {
  int s = blockIdx.x, t = threadIdx.x;
  int tk = tok[s];
  const float4* we = (const float4*)(Wemb + (size_t)tk * EMB);
  const float4* wp = (const float4*)(Wpos + (size_t)s * EMB);
  float4 a = we[t], b = wp[t];
  float4 o; o.x = a.x + b.x; o.y = a.y + b.y; o.z = a.z + b.z; o.w = a.w + b.w;
  ((float4*)(x + (size_t)s * EMB))[t] = o;
}

// ---------------- LayerNorm: f32 in -> bf16 out ----------------
__global__ __launch_bounds__(256) void ln_kernel(
    const float* __restrict__ x, const float* __restrict__ g,
    const float* __restrict__ b, us* __restrict__ out) {
  int row = blockIdx.x, t = threadIdx.x, lane = t & 63, wave = t >> 6;
  float4 v = ((const float4*)(x + (size_t)row * EMB))[t];
  float s = v.x + v.y + v.z + v.w;
  float q = v.x * v.x + v.y * v.y + v.z * v.z + v.w * v.w;
  #pragma unroll
  for (int d = 1; d < 64; d <<= 1) { s += __shfl_xor(s, d); q += __shfl_xor(q, d); }
  __shared__ float rs[4], rq[4];
  if (lane == 0) { rs[wave] = s; rq[wave] = q; }
  __syncthreads();
  s = rs[0] + rs[1] + rs[2] + rs[3];
  q = rq[0] + rq[1] + rq[2] + rq[3];
  float mean = s * (1.0f / EMB);
  float var = q * (1.0f / EMB) - mean * mean;
  float rstd = rsqrtf(var + 1e-5f);
  float4 gg = ((const float4*)g)[t], bb = ((const float4*)b)[t];
  ushort4 o;
  o.x = f2bf((v.x - mean) * rstd * gg.x + bb.x);
  o.y = f2bf((v.y - mean) * rstd * gg.y + bb.y);
  o.z = f2bf((v.z - mean) * rstd * gg.z + bb.z);
  o.w = f2bf((v.w - mean) * rstd * gg.w + bb.w);
  ((ushort4*)(out + (size_t)row * EMB))[t] = o;
}

// ---- fused: x += bias + sum_z p[z];  out = LN(x)*g + b ----
template <int SK>
__global__ __launch_bounds__(256) void reduce_ln_kernel(
    float* __restrict__ x, const float* __restrict__ p,
    const float* __restrict__ bias, const float* __restrict__ g,
    const float* __restrict__ b, us* __restrict__ out) {
  int row = blockIdx.x, t = threadIdx.x, lane = t & 63, wave = t >> 6;
  const size_t plane = (size_t)S_LEN * EMB;
  float4 v = ((const float4*)(x + (size_t)row * EMB))[t];
  float4 bb4 = ((const float4*)bias)[t];
  v.x += bb4.x; v.y += bb4.y; v.z += bb4.z; v.w += bb4.w;
  #pragma unroll
  for (int z = 0; z < SK; ++z) {
    float4 q4 = ((const float4*)(p + z * plane + (size_t)row * EMB))[t];
    v.x += q4.x; v.y += q4.y; v.z += q4.z; v.w += q4.w;
  }
  ((float4*)(x + (size_t)row * EMB))[t] = v;
  float s = v.x + v.y + v.z + v.w;
  float q = v.x * v.x + v.y * v.y + v.z * v.z + v.w * v.w;
  #pragma unroll
  for (int d = 1; d < 64; d <<= 1) { s += __shfl_xor(s, d); q += __shfl_xor(q, d); }
  __shared__ float rs[4], rq[4];
  if (lane == 0) { rs[wave] = s; rq[wave] = q; }
  __syncthreads();
  s = rs[0] + rs[1] + rs[2] + rs[3];
  q = rq[0] + rq[1] + rq[2] + rq[3];
  float mean = s * (1.0f / EMB);
  float var = q * (1.0f / EMB) - mean * mean;
  float rstd = rsqrtf(var + 1e-5f);
  float4 gg = ((const float4*)g)[t], lb = ((const float4*)b)[t];
  ushort4 o;
  o.x = f2bf((v.x - mean) * rstd * gg.x + lb.x);
  o.y = f2bf((v.y - mean) * rstd * gg.y + lb.y);
  o.z = f2bf((v.z - mean) * rstd * gg.z + lb.z);
  o.w = f2bf((v.w - mean) * rstd * gg.w + lb.w);
  ((ushort4*)(out + (size_t)row * EMB))[t] = o;
}

// ======== ring-128 GEMM: 128x128 tile, 4 waves, BK=32, 3-deep ring =========
#define STAGE_R(MATP, BROW, LDSB, TT)                                          \
  {                                                                            \
    const int kk0 = (TT) << 5;                                                 \
    _Pragma("unroll")                                                          \
    for (int i_ = 0; i_ < 2; ++i_) {                                           \
      const int ci = t + i_ * 256;                                             \
      const int rr = ci >> 2, cc = ci & 3;                                     \
      const int src = (cc ^ ((rr >> 1) & 3)) * 8;                              \
      GLOAD_LDS16(MATP + (size_t)((BROW) + rr) * K + kk0 + src,                \
                  &LDSB[0] + (wave * 64 + i_ * 256) * 8);                      \
    }                                                                          \
  }

template <int HAS_BIAS, int DO_GELU, int OUT_BF16>
__global__ __launch_bounds__(256) void gemm_r128(
    const us* __restrict__ A, const us* __restrict__ B0,
    const us* __restrict__ B1, const us* __restrict__ B2,
    const float* __restrict__ bias,
    void* C0, void* C1, void* C2, int M, int N, int K) {
  const us* B = blockIdx.z == 0 ? B0 : (blockIdx.z == 1 ? B1 : B2);
  void* C = blockIdx.z == 0 ? C0 : (blockIdx.z == 1 ? C1 : C2);
  const int nwg = gridDim.x * gridDim.y;
  int lin = blockIdx.y * gridDim.x + blockIdx.x;
  {
    const int qx = nwg >> 3, r = nwg & 7;
    const int xcd = lin & 7, idx = lin >> 3;
    lin = (xcd < r ? xcd * (qx + 1) : r * (qx + 1) + (xcd - r) * qx) + idx;
  }
  const int m0 = (lin % gridDim.x) * 128, n0 = (lin / gridDim.x) * 128;
  const int t = threadIdx.x, lane = t & 63, wave = t >> 6;
  const int lq = lane & 15, hi = lane >> 4;
  const int wm = (wave >> 1) * 64, wn = (wave & 1) * 64;
  __shared__ __align__(16) us As[3][128 * 32];
  __shared__ __align__(16) us Bs[3][128 * 32];
  f32x4 acc[4][4] = {};
  const int nt = K >> 5;

  STAGE_R(A, m0, As[0], 0); STAGE_R(B, n0, Bs[0], 0);
  STAGE_R(A, m0, As[1], 1); STAGE_R(B, n0, Bs[1], 1);
  STAGE_R(A, m0, As[2], 2); STAGE_R(B, n0, Bs[2], 2);
  asm volatile("s_waitcnt vmcnt(8)" ::: "memory");
  __builtin_amdgcn_s_barrier();
  __builtin_amdgcn_sched_barrier(0);

  int bb = 0;
  for (int tt = 0; tt < nt; ++tt) {
    const int sb = (bb + 2 >= 3) ? bb - 1 : bb + 2;
    const us* Ab = &As[bb][0];
    const us* Bb = &Bs[bb][0];
    bf16x8 a[4], b[4];
    #pragma unroll
    for (int f = 0; f < 4; ++f) {
      const int row = wm + f * 16 + lq;
      a[f] = *(const bf16x8*)(Ab + row * 32 + ((hi ^ ((row >> 1) & 3)) * 8));
    }
    #pragma unroll
    for (int f = 0; f < 4; ++f) {
      const int row = wn + f * 16 + lq;
      b[f] = *(const bf16x8*)(Bb + row * 32 + ((hi ^ ((row >> 1) & 3)) * 8));
    }
    if (tt + 2 < nt) {
      STAGE_R(A, m0, As[sb], tt + 2);
      STAGE_R(B, n0, Bs[sb], tt + 2);
    }
    __builtin_amdgcn_s_setprio(1);
    #pragma unroll
    for (int i = 0; i < 4; ++i)
      #pragma unroll
      for (int j = 0; j < 4; ++j)
        acc[i][j] = __builtin_amdgcn_mfma_f32_16x16x32_bf16(a[i], b[j], acc[i][j], 0, 0, 0);
    __builtin_amdgcn_s_setprio(0);
    if (tt + 2 < nt) {
      asm volatile("s_waitcnt vmcnt(4)" ::: "memory");
    } else {
      asm volatile("s_waitcnt vmcnt(0)" ::: "memory");
    }
    __builtin_amdgcn_s_barrier();
    __builtin_amdgcn_sched_barrier(0);
    bb = (bb + 1 == 3) ? 0 : bb + 1;
  }
  const int r0 = hi * 4;
  #pragma unroll
  for (int i = 0; i < 4; ++i) {
    #pragma unroll
    for (int j = 0; j < 4; ++j) {
      const int col = n0 + wn + j * 16 + lq;
      float bv = HAS_BIAS ? bias[col] : 0.0f;
      #pragma unroll
      for (int r = 0; r < 4; ++r) {
        const int row = m0 + wm + i * 16 + r0 + r;
        float val = acc[i][j][r] + bv;
        if (DO_GELU) val = val * 0.5f * (1.0f + erff(val * 0.70710678118f));
        if (OUT_BF16) ((us*)C)[(size_t)row * N + col] = f2bf(val);
        else          ((float*)C)[(size_t)row * N + col] = val;
      }
    }
  }
}

// ======== ring-128 split-K GEMM: f32 partials C[z][m][n] ========
__global__ __launch_bounds__(256) void gemm_rsk(
    const us* __restrict__ A, const us* __restrict__ B,
    float* __restrict__ C, int M, int N, int K, int kSlice) {
  const int z = blockIdx.z;
  const int nwg = gridDim.x * gridDim.y;
  int lin = blockIdx.y * gridDim.x + blockIdx.x;
  {
    const int qx = nwg >> 3, r = nwg & 7;
    const int xcd = lin & 7, idx = lin >> 3;
    lin = (xcd < r ? xcd * (qx + 1) : r * (qx + 1) + (xcd - r) * qx) + idx;
  }
  const int m0 = (lin % gridDim.x) * 128, n0 = (lin / gridDim.x) * 128;
  const int t = threadIdx.x, lane = t & 63, wave = t >> 6;
  const int lq = lane & 15, hi = lane >> 4;
  const int wm = (wave >> 1) * 64, wn = (wave & 1) * 64;
  __shared__ __align__(16) us As[3][128 * 32];
  __shared__ __align__(16) us Bs[3][128 * 32];
  f32x4 acc[4][4] = {};
  const int nt = kSlice >> 5;
  const int tb = z * (kSlice >> 5);

  STAGE_R(A, m0, As[0], tb + 0); STAGE_R(B, n0, Bs[0], tb + 0);
  STAGE_R(A, m0, As[1], tb + 1); STAGE_R(B, n0, Bs[1], tb + 1);
  STAGE_R(A, m0, As[2], tb + 2); STAGE_R(B, n0, Bs[2], tb + 2);
  asm volatile("s_waitcnt vmcnt(8)" ::: "memory");
  __builtin_amdgcn_s_barrier();
  __builtin_amdgcn_sched_barrier(0);

  int bb = 0;
  for (int tt = 0; tt < nt; ++tt) {
    const int sb = (bb + 2 >= 3) ? bb - 1 : bb + 2;
    const us* Ab = &As[bb][0];
    const us* Bb = &Bs[bb][0];
    bf16x8 a[4], b[4];
    #pragma unroll
    for (int f = 0; f < 4; ++f) {
      const int row = wm + f * 16 + lq;
      a[f] = *(const bf16x8*)(Ab + row * 32 + ((hi ^ ((row >> 1) & 3)) * 8));
    }
    #pragma unroll
    for (int f = 0; f < 4; ++f) {
      const int row = wn + f * 16 + lq;
      b[f] = *(const bf16x8*)(Bb + row * 32 + ((hi ^ ((row >> 1) & 3)) * 8));
    }
    if (tt + 2 < nt) {
      STAGE_R(A, m0, As[sb], tb + tt + 2);
      STAGE_R(B, n0, Bs[sb], tb + tt + 2);
    }
    __builtin_amdgcn_s_setprio(1);
    #pragma unroll
    for (int i = 0; i < 4; ++i)
      #pragma unroll
      for (int j = 0; j < 4; ++j)
        acc[i][j] = __builtin_amdgcn_mfma_f32_16x16x32_bf16(a[i], b[j], acc[i][j], 0, 0, 0);
    __builtin_amdgcn_s_setprio(0);
    if (tt + 2 < nt) {
      asm volatile("s_waitcnt vmcnt(4)" ::: "memory");
    } else {
      asm volatile("s_waitcnt vmcnt(0)" ::: "memory");
    }
    __builtin_amdgcn_s_barrier();
    __builtin_amdgcn_sched_barrier(0);
    bb = (bb + 1 == 3) ? 0 : bb + 1;
  }
  float* Cz = C + (size_t)z * M * N;
  #pragma unroll
  for (int i = 0; i < 4; ++i)
    #pragma unroll
    for (int j = 0; j < 4; ++j) {
      const int col = n0 + wn + j * 16 + lq;
      #pragma unroll
      for (int r = 0; r < 4; ++r)
        Cz[(size_t)(m0 + wm + i * 16 + hi * 4 + r) * N + col] = acc[i][j][r];
    }
}

// ------- 256x256 dbuf GEMM (vocab): ring-2, vmcnt(0)/tile, 2 blk/CU -------
// T3 "minimum 2-phase" recipe; 64KB LDS so two blocks co-reside per CU and
// cross-block wave overlap covers the per-tile drain (m97/m114 mechanism).
__global__ __launch_bounds__(512, 4) void gemm_v8p(
    const us* __restrict__ A, const us* __restrict__ B,
    float* __restrict__ C, int M, int N, int K) {
  const int nwg = gridDim.x * gridDim.y;
  int lin = blockIdx.y * gridDim.x + blockIdx.x;
  {
    const int qx = nwg >> 3, r = nwg & 7;
    const int xcd = lin & 7, idx = lin >> 3;
    lin = (xcd < r ? xcd * (qx + 1) : r * (qx + 1) + (xcd - r) * qx) + idx;
  }
  const int m0 = (lin % gridDim.x) * 256, n0 = (lin / gridDim.x) * 256;
  const int t = threadIdx.x, lane = t & 63, wave = t >> 6;
  const int lq = lane & 15, hi = lane >> 4;
  const int rbase = (wave >> 2) * 128, cbase = (wave & 3) * 64;
  __shared__ __align__(16) us As[2][256 * 32];
  __shared__ __align__(16) us Bs[2][256 * 32];
  f32x4 acc[8][4] = {};
  const int nt = K >> 5;

#define STAGE_T(MAT, LDSB, TT)                                                 \
  {                                                                            \
    const int kk0 = (TT) << 5;                                                 \
    _Pragma("unroll")                                                          \
    for (int i_ = 0; i_ < 2; ++i_) {                                           \
      const int ci = t + i_ * 512;                                             \
      const int rr = ci >> 2, cc = ci & 3;                                     \
      const int src = (cc ^ ((rr >> 1) & 3)) * 8;                              \
      GLOAD_LDS16(MAT + (size_t)(((MAT == A) ? m0 : n0) + rr) * K + kk0 + src, \
                  &LDSB[0] + (wave * 64 + i_ * 512) * 8);                      \
    }                                                                          \
  }

  // prologue: stage tile 0 only
  STAGE_T(A, As[0], 0); STAGE_T(B, Bs[0], 0);
  asm volatile("s_waitcnt vmcnt(0)" ::: "memory");
  __builtin_amdgcn_s_barrier();
  __builtin_amdgcn_sched_barrier(0);

  int cur = 0;
  for (int tt = 0; tt < nt; ++tt) {
    // issue next-tile loads into the other buffer (its last reads retired
    // before the barrier that ended tile tt-1)
    if (tt + 1 < nt) {
      STAGE_T(A, As[cur ^ 1], tt + 1);
      STAGE_T(B, Bs[cur ^ 1], tt + 1);
    }
    const us* Ab = &As[cur][0];
    const us* Bb = &Bs[cur][0];
    bf16x8 a0[4], a1[4], b0[4];
    #pragma unroll
    for (int f = 0; f < 4; ++f) {
      const int row = rbase + f * 16 + lq;
      a0[f] = *(const bf16x8*)(Ab + row * 32 + ((hi ^ ((row >> 1) & 3)) * 8));
    }
    #pragma unroll
    for (int f = 0; f < 4; ++f) {
      const int row = rbase + 64 + f * 16 + lq;
      a1[f] = *(const bf16x8*)(Ab + row * 32 + ((hi ^ ((row >> 1) & 3)) * 8));
    }
    #pragma unroll
    for (int f = 0; f < 4; ++f) {
      const int row = cbase + f * 16 + lq;
      b0[f] = *(const bf16x8*)(Bb + row * 32 + ((hi ^ ((row >> 1) & 3)) * 8));
    }
    __builtin_amdgcn_s_setprio(1);
    #pragma unroll
    for (int i = 0; i < 4; ++i)
      #pragma unroll
      for (int j = 0; j < 4; ++j)
        acc[i][j] = __builtin_amdgcn_mfma_f32_16x16x32_bf16(a0[i], b0[j], acc[i][j], 0, 0, 0);
    #pragma unroll
    for (int i = 0; i < 4; ++i)
      #pragma unroll
      for (int j = 0; j < 4; ++j)
        acc[4 + i][j] = __builtin_amdgcn_mfma_f32_16x16x32_bf16(a1[i], b0[j], acc[4 + i][j], 0, 0, 0);
    __builtin_amdgcn_s_setprio(0);
    asm volatile("s_waitcnt vmcnt(0)" ::: "memory");  // next tile landed (mine)
    __builtin_amdgcn_s_barrier();                     // visible to all waves
    __builtin_amdgcn_sched_barrier(0);
    cur ^= 1;
  }
#undef STAGE_T
  #pragma unroll
  for (int i = 0; i < 8; ++i)
    #pragma unroll
    for (int j = 0; j < 4; ++j) {
      const int col = n0 + cbase + j * 16 + lq;
      #pragma unroll
      for (int r = 0; r < 4; ++r)
        C[(size_t)(m0 + rbase + i * 16 + hi * 4 + r) * N + col] = acc[i][j][r];
    }
}

// ---- flash attention v7: CU-paired balance, single pass, 2 blk/CU ----
__global__ __launch_bounds__(256) void attn_kernel(
    const us* __restrict__ qb, const us* __restrict__ kb,
    const us* __restrict__ vb, us* __restrict__ ob) {
  const int head = blockIdx.y;
  const int qt = (head < 8) ? (int)blockIdx.x : 31 - (int)blockIdx.x;
  const int t = threadIdx.x, lane = t & 63, wave = t >> 6;
  const int hi = lane >> 4, lq = lane & 15;
  const int hd = head * HDIM;
  const int q0w = qt * 64 + wave * 16;
  __shared__ __align__(16) us Kl[2][64 * 64];   // XOR-swizzled
  __shared__ __align__(16) us Vl[2][64 * 72];   // V^T padded
  __shared__ __align__(16) us Pl[4][16][72];
  bf16x8 qf[2];
  {
    const us* qp = qb + (size_t)(q0w + lq) * EMB + hd + hi * 8;
    qf[0] = *(const bf16x8*)qp;
    qf[1] = *(const bf16x8*)(qp + 32);
    #pragma unroll
    for (int e = 0; e < 8; ++e) {
      qf[0][e] = (__bf16)((float)qf[0][e] * 0.125f);
      qf[1][e] = (__bf16)((float)qf[1][e] * 0.125f);
    }
  }
  f32x4 accO[4] = {};
  float m_run = -1e30f, l_run = 0.f;
  const int vr2 = (t >> 3) * 2, d8 = (t & 7) * 8;
  const int q_g = q0w + lq;

  {
    #pragma unroll
    for (int i = 0; i < 2; ++i) {
      const int c = wave * 64 + lane + i * 256;
      const int row = c >> 3, j = c & 7;
      const int colE = (j * 8) ^ ((row & 7) << 3);
      GLOAD_LDS16(kb + (size_t)(row) * EMB + hd + colE,
                  &Kl[0][0] + (wave * 64 + i * 256) * 8);
    }
    const us* vp = vb + (size_t)vr2 * EMB + hd + d8;
    uint4 vA = *(const uint4*)vp;
    uint4 vB = *(const uint4*)(vp + EMB);
    const unsigned* wa = (const unsigned*)&vA;
    const unsigned* wb = (const unsigned*)&vB;
    #pragma unroll
    for (int i = 0; i < 8; ++i) {
      unsigned lo = (i & 1) ? (wa[i >> 1] >> 16) : (wa[i >> 1] & 0xffffu);
      unsigned hw = (i & 1) ? (wb[i >> 1] >> 16) : (wb[i >> 1] & 0xffffu);
      *(unsigned*)(&Vl[0][0] + (d8 + i) * 72 + vr2) = lo | (hw << 16);
    }
  }
  __syncthreads();
  int cur = 0;
  for (int kt = 0; kt <= qt; ++kt) {
    uint4 vA, vB;
    if (kt < qt) {
      #pragma unroll
      for (int i = 0; i < 2; ++i) {
        const int c = wave * 64 + lane + i * 256;
        const int row = c >> 3, j = c & 7;
        const int colE = (j * 8) ^ ((row & 7) << 3);
        GLOAD_LDS16(kb + (size_t)((kt + 1) * 64 + row) * EMB + hd + colE,
                    &Kl[cur ^ 1][0] + (wave * 64 + i * 256) * 8);
      }
      const us* vp = vb + (size_t)((kt + 1) * 64 + vr2) * EMB + hd + d8;
      vA = *(const uint4*)vp;
      vB = *(const uint4*)(vp + EMB);
    }
    f32x4 sc[4] = {};
    #pragma unroll
    for (int ks = 0; ks < 2; ++ks) {
      #pragma unroll
      for (int fn = 0; fn < 4; ++fn) {
        const int rowk = fn * 16 + lq;
        const us* kp = &Kl[cur][0] + rowk * 64 + ((ks * 32 + hi * 8) ^ ((rowk & 7) << 3));
        sc[fn] = __builtin_amdgcn_mfma_f32_16x16x32_bf16(
            *(const bf16x8*)kp, qf[ks], sc[fn], 0, 0, 0);
      }
    }
    float pv[16];
    float pmax = -1e30f;
    if (kt == qt) {
      #pragma unroll
      for (int fn = 0; fn < 4; ++fn)
        #pragma unroll
        for (int r = 0; r < 4; ++r) {
          const int k_g = kt * 64 + fn * 16 + hi * 4 + r;
          float sv = sc[fn][r];
          if (k_g > q_g) sv = -1e30f;
          pv[fn * 4 + r] = sv;
          pmax = fmaxf(pmax, sv);
        }
    } else {
      #pragma unroll
      for (int fn = 0; fn < 4; ++fn)
        #pragma unroll
        for (int r = 0; r < 4; ++r) {
          float sv = sc[fn][r];
          pv[fn * 4 + r] = sv;
          pmax = fmaxf(pmax, sv);
        }
    }
    pmax = fmaxf(pmax, __shfl_xor(pmax, 16));
    pmax = fmaxf(pmax, __shfl_xor(pmax, 32));
    if (!__all(pmax <= m_run + 8.0f)) {
      const float mn = fmaxf(m_run, pmax);
      const float alpha = __expf(m_run - mn);
      m_run = mn;
      l_run *= alpha;
      float ar[4];
      #pragma unroll
      for (int r = 0; r < 4; ++r) ar[r] = __shfl(alpha, hi * 4 + r);
      #pragma unroll
      for (int df = 0; df < 4; ++df)
        #pragma unroll
        for (int r = 0; r < 4; ++r) accO[df][r] *= ar[r];
    }
    float rsum = 0.f;
    #pragma unroll
    for (int i = 0; i < 16; ++i) {
      float e = __expf(pv[i] - m_run);
      pv[i] = e;
      rsum += e;
    }
    rsum += __shfl_xor(rsum, 16);
    rsum += __shfl_xor(rsum, 32);
    l_run += rsum;
    #pragma unroll
    for (int fn = 0; fn < 4; ++fn) {
      ushort4 pk;
      pk.x = f2bf(pv[fn * 4 + 0]);
      pk.y = f2bf(pv[fn * 4 + 1]);
      pk.z = f2bf(pv[fn * 4 + 2]);
      pk.w = f2bf(pv[fn * 4 + 3]);
      *(ushort4*)&Pl[wave][lq][fn * 16 + hi * 4] = pk;
    }
    #pragma unroll
    for (int ks = 0; ks < 2; ++ks) {
      bf16x8 pf = *(const bf16x8*)&Pl[wave][lq][ks * 32 + hi * 8];
      #pragma unroll
      for (int df = 0; df < 4; ++df) {
        bf16x8 vf = *(const bf16x8*)(&Vl[cur][0] + (df * 16 + lq) * 72 + ks * 32 + hi * 8);
        accO[df] = __builtin_amdgcn_mfma_f32_16x16x32_bf16(pf, vf, accO[df], 0, 0, 0);
      }
    }
    if (kt < qt) {
      const unsigned* wa = (const unsigned*)&vA;
      const unsigned* wb = (const unsigned*)&vB;
      #pragma unroll
      for (int i = 0; i < 8; ++i) {
        unsigned lo = (i & 1) ? (wa[i >> 1] >> 16) : (wa[i >> 1] & 0xffffu);
        unsigned hw = (i & 1) ? (wb[i >> 1] >> 16) : (wb[i >> 1] & 0xffffu);
        *(unsigned*)(&Vl[cur ^ 1][0] + (d8 + i) * 72 + vr2) = lo | (hw << 16);
      }
    }
    __syncthreads();
    cur ^= 1;
  }
  float linv[4];
  #pragma unroll
  for (int r = 0; r < 4; ++r) linv[r] = 1.0f / __shfl(l_run, hi * 4 + r);
  #pragma unroll
  for (int r = 0; r < 4; ++r) {
    const int row = q0w + hi * 4 + r;
    #pragma unroll
    for (int df = 0; df < 4; ++df)
      ob[(size_t)row * EMB + hd + df * 16 + lq] = f2bf(accO[df][r] * linv[r]);
  }
}

// ---------------- host ----------------
extern "C" void kernel_launch(void* const* d_in, const int* in_sizes, int n_in,
                              void* d_out, int out_size, void* d_ws, size_t ws_size,
                              hipStream_t stream) {
  const int* tok = (const int*)d_in[0];
  const float* Wemb = (const float*)d_in[1];
  const float* Wpos = (const float*)d_in[2];
  const float* Wq = (const float*)d_in[3];
  const float* Wk = (const float*)d_in[4];
  const float* Wv = (const float*)d_in[5];
  const float* Wo = (const float*)d_in[6];
  const float* bo = (const float*)d_in[7];
  const float* ln1g = (const float*)d_in[8];
  const float* ln1b = (const float*)d_in[9];
  const float* ln2g = (const float*)d_in[10];
  const float* ln2b = (const float*)d_in[11];
  const float* W1 = (const float*)d_in[12];
  const float* b1 = (const float*)d_in[13];
  const float* W2 = (const float*)d_in[14];
  const float* b2 = (const float*)d_in[15];
  const float* lnfg = (const float*)d_in[16];
  const float* lnfb = (const float*)d_in[17];
  (void)in_sizes; (void)n_in; (void)out_size;

  const size_t MB = 1u << 20;
  char* ws = (char*)d_ws;
  float* x = (float*)ws;                       // [0, 8MB)
  us* h  = (us*)(ws + 8 * MB);
  us* qb = (us*)(ws + 12 * MB);
  us* kb = (us*)(ws + 16 * MB);
  us* vb = (us*)(ws + 20 * MB);
  us* ob = (us*)(ws + 24 * MB);
  us* fb = (us*)(ws + 12 * MB);                // alias qb..ob (phase-disjoint)
  us* cWq = (us*)(ws + 28 * MB);
  us* cWk = (us*)(ws + 40 * MB);
  us* cWv = (us*)(ws + 52 * MB);
  us* cWo = (us*)(ws + 64 * MB);
  us* cW1 = (us*)(ws + 76 * MB);
  us* cW2 = (us*)(ws + 124 * MB);
  us* cWemb = (us*)(ws + 172 * MB);            // ends ~234.5 MB
  float* pbuf = (float*)(ws + 236 * MB);
  const size_t need = 236 * MB + 32 * MB;
  if (ws_size < need) {
    embed_kernel<<<dim3(S_LEN), 256, 0, stream>>>(tok, Wemb, Wpos, x);
    return;
  }

  embed_kernel<<<dim3(S_LEN), 256, 0, stream>>>(tok, Wemb, Wpos, x);

  const long nE2 = (long)NLAYER * EMB * EMB;
  const long nF  = (long)NLAYER * FFDIM * EMB;
  const long nV  = (long)VOCAB * EMB;
  cvt_bf16_kernel<<<(int)(nE2 / 2048), 256, 0, stream>>>(Wq, cWq, nE2);
  cvt_bf16_kernel<<<(int)(nE2 / 2048), 256, 0, stream>>>(Wk, cWk, nE2);
  cvt_bf16_kernel<<<(int)(nE2 / 2048), 256, 0, stream>>>(Wv, cWv, nE2);
  cvt_bf16_kernel<<<(int)(nE2 / 2048), 256, 0, stream>>>(Wo, cWo, nE2);
  cvt_bf16_kernel<<<(int)(nF / 2048), 256, 0, stream>>>(W1, cW1, nF);
  cvt_bf16_kernel<<<(int)(nF / 2048), 256, 0, stream>>>(W2, cW2, nF);
  cvt_bf16_kernel<<<(int)(nV / 2048), 256, 0, stream>>>(Wemb, cWemb, nV);

  ln_kernel<<<S_LEN, 256, 0, stream>>>(x, ln1g, ln1b, h);  // layer-0 ln1
  for (int l = 0; l < NLAYER; ++l) {
    const size_t wofs = (size_t)l * EMB * EMB;
    const size_t fofs = (size_t)l * FFDIM * EMB;
    gemm_r128<0, 0, 1><<<dim3(16, 8, 3), 256, 0, stream>>>(
        h, cWq + wofs, cWk + wofs, cWv + wofs, nullptr,
        qb, kb, vb, S_LEN, EMB, EMB);
    attn_kernel<<<dim3(32, NHEAD), 256, 0, stream>>>(qb, kb, vb, ob);
    gemm_rsk<<<dim3(16, 8, 2), 256, 0, stream>>>(
        ob, cWo + wofs, pbuf, S_LEN, EMB, EMB, EMB / 2);
    reduce_ln_kernel<2><<<S_LEN, 256, 0, stream>>>(
        x, pbuf, bo + l * EMB, ln2g + l * EMB, ln2b + l * EMB, h);
    gemm_r128<1, 1, 1><<<dim3(16, 32, 1), 256, 0, stream>>>(
        h, cW1 + fofs, nullptr, nullptr, b1 + l * FFDIM,
        fb, nullptr, nullptr, S_LEN, FFDIM, EMB);
    gemm_rsk<<<dim3(16, 8, 4), 256, 0, stream>>>(
        fb, cW2 + fofs, pbuf, S_LEN, EMB, FFDIM, FFDIM / 4);
    if (l < NLAYER - 1)
      reduce_ln_kernel<4><<<S_LEN, 256, 0, stream>>>(
          x, pbuf, b2 + l * EMB, ln1g + (l + 1) * EMB, ln1b + (l + 1) * EMB, h);
    else
      reduce_ln_kernel<4><<<S_LEN, 256, 0, stream>>>(
          x, pbuf, b2 + l * EMB, lnfg, lnfb, h);
  }
  gemm_v8p<<<dim3(8, 125), 512, 0, stream>>>(
      h, cWemb, (float*)d_out, S_LEN, VOCAB, EMB);
}

// Round 16
// 1344.127 us; speedup vs baseline: 1.8611x; 1.8611x over previous
//
#include <hip/hip_runtime.h>
#include <math.h>

#define S_LEN 2048
#define EMB 1024
#define NHEAD 16
#define HDIM 64
#define NLAYER 6
#define VOCAB 32000
#define FFDIM 4096

using f32x4 = __attribute__((ext_vector_type(4))) float;
using bf16x8 = __attribute__((ext_vector_type(8))) __bf16;
typedef unsigned short us;

static __device__ __forceinline__ unsigned short f2bf(float f) {
  union { float f; unsigned int u; } v; v.f = f;
  unsigned int r = v.u + 0x7FFFu + ((v.u >> 16) & 1u);
  return (unsigned short)(r >> 16);
}

#define GLOAD_LDS16(g, l)                                                      \
  __builtin_amdgcn_global_load_lds(                                            \
      (const __attribute__((address_space(1))) void*)(g),                      \
      (__attribute__((address_space(3))) void*)(l), 16, 0, 0)

// ---------------- f32 -> bf16 bulk convert ----------------
__global__ __launch_bounds__(256) void cvt_bf16_kernel(
    const float* __restrict__ in, us* __restrict__ out, long n) {
  long i = ((long)blockIdx.x * 256 + threadIdx.x) * 8;
  if (i >= n) return;
  const float4* p = (const float4*)(in + i);
  float4 a = p[0], b = p[1];
  uint4 o;
  o.x = (unsigned)f2bf(a.x) | ((unsigned)f2bf(a.y) << 16);
  o.y = (unsigned)f2bf(a.z) | ((unsigned)f2bf(a.w) << 16);
  o.z = (unsigned)f2bf(b.x) | ((unsigned)f2bf(b.y) << 16);
  o.w = (unsigned)f2bf(b.z) | ((unsigned)f2bf(b.w) << 16);
  *(uint4*)(out + i) = o;
}

// ---------------- embedding ----------------
__global__ __launch_bounds__(256) void embed_kernel(
    const int* __restrict__ tok, const float* __restrict__ Wemb,
    const float* __restrict__ Wpos, float* __restrict__ x) {
  int s = blockIdx.x, t = threadIdx.x;
  int tk = tok[s];
  const float4* we = (const float4*)(Wemb + (size_t)tk * EMB);
  const float4* wp = (const float4*)(Wpos + (size_t)s * EMB);
  float4 a = we[t], b = wp[t];
  float4 o; o.x = a.x + b.x; o.y = a.y + b.y; o.z = a.z + b.z; o.w = a.w + b.w;
  ((float4*)(x + (size_t)s * EMB))[t] = o;
}

// ---------------- LayerNorm: f32 in -> bf16 out ----------------
__global__ __launch_bounds__(256) void ln_kernel(
    const float* __restrict__ x, const float* __restrict__ g,
    const float* __restrict__ b, us* __restrict__ out) {
  int row = blockIdx.x, t = threadIdx.x, lane = t & 63, wave = t >> 6;
  float4 v = ((const float4*)(x + (size_t)row * EMB))[t];
  float s = v.x + v.y + v.z + v.w;
  float q = v.x * v.x + v.y * v.y + v.z * v.z + v.w * v.w;
  #pragma unroll
  for (int d = 1; d < 64; d <<= 1) { s += __shfl_xor(s, d); q += __shfl_xor(q, d); }
  __shared__ float rs[4], rq[4];
  if (lane == 0) { rs[wave] = s; rq[wave] = q; }
  __syncthreads();
  s = rs[0] + rs[1] + rs[2] + rs[3];
  q = rq[0] + rq[1] + rq[2] + rq[3];
  float mean = s * (1.0f / EMB);
  float var = q * (1.0f / EMB) - mean * mean;
  float rstd = rsqrtf(var + 1e-5f);
  float4 gg = ((const float4*)g)[t], bb = ((const float4*)b)[t];
  ushort4 o;
  o.x = f2bf((v.x - mean) * rstd * gg.x + bb.x);
  o.y = f2bf((v.y - mean) * rstd * gg.y + bb.y);
  o.z = f2bf((v.z - mean) * rstd * gg.z + bb.z);
  o.w = f2bf((v.w - mean) * rstd * gg.w + bb.w);
  ((ushort4*)(out + (size_t)row * EMB))[t] = o;
}

// ---- fused: x += bias + sum_z p[z];  out = LN(x)*g + b ----
template <int SK>
__global__ __launch_bounds__(256) void reduce_ln_kernel(
    float* __restrict__ x, const float* __restrict__ p,
    const float* __restrict__ bias, const float* __restrict__ g,
    const float* __restrict__ b, us* __restrict__ out) {
  int row = blockIdx.x, t = threadIdx.x, lane = t & 63, wave = t >> 6;
  const size_t plane = (size_t)S_LEN * EMB;
  float4 v = ((const float4*)(x + (size_t)row * EMB))[t];
  float4 bb4 = ((const float4*)bias)[t];
  v.x += bb4.x; v.y += bb4.y; v.z += bb4.z; v.w += bb4.w;
  #pragma unroll
  for (int z = 0; z < SK; ++z) {
    float4 q4 = ((const float4*)(p + z * plane + (size_t)row * EMB))[t];
    v.x += q4.x; v.y += q4.y; v.z += q4.z; v.w += q4.w;
  }
  ((float4*)(x + (size_t)row * EMB))[t] = v;
  float s = v.x + v.y + v.z + v.w;
  float q = v.x * v.x + v.y * v.y + v.z * v.z + v.w * v.w;
  #pragma unroll
  for (int d = 1; d < 64; d <<= 1) { s += __shfl_xor(s, d); q += __shfl_xor(q, d); }
  __shared__ float rs[4], rq[4];
  if (lane == 0) { rs[wave] = s; rq[wave] = q; }
  __syncthreads();
  s = rs[0] + rs[1] + rs[2] + rs[3];
  q = rq[0] + rq[1] + rq[2] + rq[3];
  float mean = s * (1.0f / EMB);
  float var = q * (1.0f / EMB) - mean * mean;
  float rstd = rsqrtf(var + 1e-5f);
  float4 gg = ((const float4*)g)[t], lb = ((const float4*)b)[t];
  ushort4 o;
  o.x = f2bf((v.x - mean) * rstd * gg.x + lb.x);
  o.y = f2bf((v.y - mean) * rstd * gg.y + lb.y);
  o.z = f2bf((v.z - mean) * rstd * gg.z + lb.z);
  o.w = f2bf((v.w - mean) * rstd * gg.w + lb.w);
  ((ushort4*)(out + (size_t)row * EMB))[t] = o;
}

// ======== ring-128 GEMM: 128x128 tile, 4 waves, BK=32, 3-deep ring =========
#define STAGE_R(MATP, BROW, LDSB, TT)                                          \
  {                                                                            \
    const int kk0 = (TT) << 5;                                                 \
    _Pragma("unroll")                                                          \
    for (int i_ = 0; i_ < 2; ++i_) {                                           \
      const int ci = t + i_ * 256;                                             \
      const int rr = ci >> 2, cc = ci & 3;                                     \
      const int src = (cc ^ ((rr >> 1) & 3)) * 8;                              \
      GLOAD_LDS16(MATP + (size_t)((BROW) + rr) * K + kk0 + src,                \
                  &LDSB[0] + (wave * 64 + i_ * 256) * 8);                      \
    }                                                                          \
  }

template <int HAS_BIAS, int DO_GELU, int OUT_BF16>
__global__ __launch_bounds__(256) void gemm_r128(
    const us* __restrict__ A, const us* __restrict__ B0,
    const us* __restrict__ B1, const us* __restrict__ B2,
    const float* __restrict__ bias,
    void* C0, void* C1, void* C2, int M, int N, int K) {
  const us* B = blockIdx.z == 0 ? B0 : (blockIdx.z == 1 ? B1 : B2);
  void* C = blockIdx.z == 0 ? C0 : (blockIdx.z == 1 ? C1 : C2);
  const int nwg = gridDim.x * gridDim.y;
  int lin = blockIdx.y * gridDim.x + blockIdx.x;
  {
    const int qx = nwg >> 3, r = nwg & 7;
    const int xcd = lin & 7, idx = lin >> 3;
    lin = (xcd < r ? xcd * (qx + 1) : r * (qx + 1) + (xcd - r) * qx) + idx;
  }
  const int m0 = (lin % gridDim.x) * 128, n0 = (lin / gridDim.x) * 128;
  const int t = threadIdx.x, lane = t & 63, wave = t >> 6;
  const int lq = lane & 15, hi = lane >> 4;
  const int wm = (wave >> 1) * 64, wn = (wave & 1) * 64;
  __shared__ __align__(16) us As[3][128 * 32];
  __shared__ __align__(16) us Bs[3][128 * 32];
  f32x4 acc[4][4] = {};
  const int nt = K >> 5;

  STAGE_R(A, m0, As[0], 0); STAGE_R(B, n0, Bs[0], 0);
  STAGE_R(A, m0, As[1], 1); STAGE_R(B, n0, Bs[1], 1);
  STAGE_R(A, m0, As[2], 2); STAGE_R(B, n0, Bs[2], 2);
  asm volatile("s_waitcnt vmcnt(8)" ::: "memory");
  __builtin_amdgcn_s_barrier();
  __builtin_amdgcn_sched_barrier(0);

  int bb = 0;
  for (int tt = 0; tt < nt; ++tt) {
    const int sb = (bb + 2 >= 3) ? bb - 1 : bb + 2;
    const us* Ab = &As[bb][0];
    const us* Bb = &Bs[bb][0];
    bf16x8 a[4], b[4];
    #pragma unroll
    for (int f = 0; f < 4; ++f) {
      const int row = wm + f * 16 + lq;
      a[f] = *(const bf16x8*)(Ab + row * 32 + ((hi ^ ((row >> 1) & 3)) * 8));
    }
    #pragma unroll
    for (int f = 0; f < 4; ++f) {
      const int row = wn + f * 16 + lq;
      b[f] = *(const bf16x8*)(Bb + row * 32 + ((hi ^ ((row >> 1) & 3)) * 8));
    }
    if (tt + 2 < nt) {
      STAGE_R(A, m0, As[sb], tt + 2);
      STAGE_R(B, n0, Bs[sb], tt + 2);
    }
    __builtin_amdgcn_s_setprio(1);
    #pragma unroll
    for (int i = 0; i < 4; ++i)
      #pragma unroll
      for (int j = 0; j < 4; ++j)
        acc[i][j] = __builtin_amdgcn_mfma_f32_16x16x32_bf16(a[i], b[j], acc[i][j], 0, 0, 0);
    __builtin_amdgcn_s_setprio(0);
    if (tt + 2 < nt) {
      asm volatile("s_waitcnt vmcnt(4)" ::: "memory");
    } else {
      asm volatile("s_waitcnt vmcnt(0)" ::: "memory");
    }
    __builtin_amdgcn_s_barrier();
    __builtin_amdgcn_sched_barrier(0);
    bb = (bb + 1 == 3) ? 0 : bb + 1;
  }
  const int r0 = hi * 4;
  #pragma unroll
  for (int i = 0; i < 4; ++i) {
    #pragma unroll
    for (int j = 0; j < 4; ++j) {
      const int col = n0 + wn + j * 16 + lq;
      float bv = HAS_BIAS ? bias[col] : 0.0f;
      #pragma unroll
      for (int r = 0; r < 4; ++r) {
        const int row = m0 + wm + i * 16 + r0 + r;
        float val = acc[i][j][r] + bv;
        if (DO_GELU) val = val * 0.5f * (1.0f + erff(val * 0.70710678118f));
        if (OUT_BF16) ((us*)C)[(size_t)row * N + col] = f2bf(val);
        else          ((float*)C)[(size_t)row * N + col] = val;
      }
    }
  }
}

// ======== ring-128 split-K GEMM: f32 partials C[z][m][n] ========
__global__ __launch_bounds__(256) void gemm_rsk(
    const us* __restrict__ A, const us* __restrict__ B,
    float* __restrict__ C, int M, int N, int K, int kSlice) {
  const int z = blockIdx.z;
  const int nwg = gridDim.x * gridDim.y;
  int lin = blockIdx.y * gridDim.x + blockIdx.x;
  {
    const int qx = nwg >> 3, r = nwg & 7;
    const int xcd = lin & 7, idx = lin >> 3;
    lin = (xcd < r ? xcd * (qx + 1) : r * (qx + 1) + (xcd - r) * qx) + idx;
  }
  const int m0 = (lin % gridDim.x) * 128, n0 = (lin / gridDim.x) * 128;
  const int t = threadIdx.x, lane = t & 63, wave = t >> 6;
  const int lq = lane & 15, hi = lane >> 4;
  const int wm = (wave >> 1) * 64, wn = (wave & 1) * 64;
  __shared__ __align__(16) us As[3][128 * 32];
  __shared__ __align__(16) us Bs[3][128 * 32];
  f32x4 acc[4][4] = {};
  const int nt = kSlice >> 5;
  const int tb = z * (kSlice >> 5);

  STAGE_R(A, m0, As[0], tb + 0); STAGE_R(B, n0, Bs[0], tb + 0);
  STAGE_R(A, m0, As[1], tb + 1); STAGE_R(B, n0, Bs[1], tb + 1);
  STAGE_R(A, m0, As[2], tb + 2); STAGE_R(B, n0, Bs[2], tb + 2);
  asm volatile("s_waitcnt vmcnt(8)" ::: "memory");
  __builtin_amdgcn_s_barrier();
  __builtin_amdgcn_sched_barrier(0);

  int bb = 0;
  for (int tt = 0; tt < nt; ++tt) {
    const int sb = (bb + 2 >= 3) ? bb - 1 : bb + 2;
    const us* Ab = &As[bb][0];
    const us* Bb = &Bs[bb][0];
    bf16x8 a[4], b[4];
    #pragma unroll
    for (int f = 0; f < 4; ++f) {
      const int row = wm + f * 16 + lq;
      a[f] = *(const bf16x8*)(Ab + row * 32 + ((hi ^ ((row >> 1) & 3)) * 8));
    }
    #pragma unroll
    for (int f = 0; f < 4; ++f) {
      const int row = wn + f * 16 + lq;
      b[f] = *(const bf16x8*)(Bb + row * 32 + ((hi ^ ((row >> 1) & 3)) * 8));
    }
    if (tt + 2 < nt) {
      STAGE_R(A, m0, As[sb], tb + tt + 2);
      STAGE_R(B, n0, Bs[sb], tb + tt + 2);
    }
    __builtin_amdgcn_s_setprio(1);
    #pragma unroll
    for (int i = 0; i < 4; ++i)
      #pragma unroll
      for (int j = 0; j < 4; ++j)
        acc[i][j] = __builtin_amdgcn_mfma_f32_16x16x32_bf16(a[i], b[j], acc[i][j], 0, 0, 0);
    __builtin_amdgcn_s_setprio(0);
    if (tt + 2 < nt) {
      asm volatile("s_waitcnt vmcnt(4)" ::: "memory");
    } else {
      asm volatile("s_waitcnt vmcnt(0)" ::: "memory");
    }
    __builtin_amdgcn_s_barrier();
    __builtin_amdgcn_sched_barrier(0);
    bb = (bb + 1 == 3) ? 0 : bb + 1;
  }
  float* Cz = C + (size_t)z * M * N;
  #pragma unroll
  for (int i = 0; i < 4; ++i)
    #pragma unroll
    for (int j = 0; j < 4; ++j) {
      const int col = n0 + wn + j * 16 + lq;
      #pragma unroll
      for (int r = 0; r < 4; ++r)
        Cz[(size_t)(m0 + wm + i * 16 + hi * 4 + r) * N + col] = acc[i][j][r];
    }
}

// ------- 256x256 ring GEMM (vocab projection) — R14 version, ring-3 -------
__global__ __launch_bounds__(512, 1) void gemm_v8p(
    const us* __restrict__ A, const us* __restrict__ B,
    float* __restrict__ C, int M, int N, int K) {
  const int nwg = gridDim.x * gridDim.y;
  int lin = blockIdx.y * gridDim.x + blockIdx.x;
  {
    const int qx = nwg >> 3, r = nwg & 7;
    const int xcd = lin & 7, idx = lin >> 3;
    lin = (xcd < r ? xcd * (qx + 1) : r * (qx + 1) + (xcd - r) * qx) + idx;
  }
  const int m0 = (lin % gridDim.x) * 256, n0 = (lin / gridDim.x) * 256;
  const int t = threadIdx.x, lane = t & 63, wave = t >> 6;
  const int lq = lane & 15, hi = lane >> 4;
  const int rbase = (wave >> 2) * 128, cbase = (wave & 3) * 64;
  __shared__ __align__(16) us As[3][256 * 32];
  __shared__ __align__(16) us Bs[3][256 * 32];
  f32x4 acc[8][4] = {};
  const int nt = K >> 5;

#define STAGE_T(MAT, LDSB, TT)                                                 \
  {                                                                            \
    const int kk0 = (TT) << 5;                                                 \
    _Pragma("unroll")                                                          \
    for (int i_ = 0; i_ < 2; ++i_) {                                           \
      const int ci = t + i_ * 512;                                             \
      const int rr = ci >> 2, cc = ci & 3;                                     \
      const int src = (cc ^ ((rr >> 1) & 3)) * 8;                              \
      GLOAD_LDS16(MAT + (size_t)(((MAT == A) ? m0 : n0) + rr) * K + kk0 + src, \
                  &LDSB[0] + (wave * 64 + i_ * 512) * 8);                      \
    }                                                                          \
  }

  STAGE_T(A, As[0], 0); STAGE_T(B, Bs[0], 0);
  STAGE_T(A, As[1], 1); STAGE_T(B, Bs[1], 1);
  STAGE_T(A, As[2], 2); STAGE_T(B, Bs[2], 2);
  asm volatile("s_waitcnt vmcnt(8)" ::: "memory");
  __builtin_amdgcn_s_barrier();
  __builtin_amdgcn_sched_barrier(0);

  int bb = 0;
  for (int tt = 0; tt < nt; ++tt) {
    const int sb = (bb + 2 >= 3) ? bb - 1 : bb + 2;
    const us* Ab = &As[bb][0];
    const us* Bb = &Bs[bb][0];
    bf16x8 a0[4], a1[4], b0[4];
    #pragma unroll
    for (int f = 0; f < 4; ++f) {
      const int row = rbase + f * 16 + lq;
      a0[f] = *(const bf16x8*)(Ab + row * 32 + ((hi ^ ((row >> 1) & 3)) * 8));
    }
    #pragma unroll
    for (int f = 0; f < 4; ++f) {
      const int row = rbase + 64 + f * 16 + lq;
      a1[f] = *(const bf16x8*)(Ab + row * 32 + ((hi ^ ((row >> 1) & 3)) * 8));
    }
    #pragma unroll
    for (int f = 0; f < 4; ++f) {
      const int row = cbase + f * 16 + lq;
      b0[f] = *(const bf16x8*)(Bb + row * 32 + ((hi ^ ((row >> 1) & 3)) * 8));
    }
    if (tt + 2 < nt) {
      STAGE_T(A, As[sb], tt + 2);
      STAGE_T(B, Bs[sb], tt + 2);
    }
    __builtin_amdgcn_s_setprio(1);
    #pragma unroll
    for (int i = 0; i < 4; ++i)
      #pragma unroll
      for (int j = 0; j < 4; ++j)
        acc[i][j] = __builtin_amdgcn_mfma_f32_16x16x32_bf16(a0[i], b0[j], acc[i][j], 0, 0, 0);
    #pragma unroll
    for (int i = 0; i < 4; ++i)
      #pragma unroll
      for (int j = 0; j < 4; ++j)
        acc[4 + i][j] = __builtin_amdgcn_mfma_f32_16x16x32_bf16(a1[i], b0[j], acc[4 + i][j], 0, 0, 0);
    __builtin_amdgcn_s_setprio(0);
    if (tt + 2 < nt) {
      asm volatile("s_waitcnt vmcnt(4)" ::: "memory");
    } else {
      asm volatile("s_waitcnt vmcnt(0)" ::: "memory");
    }
    __builtin_amdgcn_s_barrier();
    __builtin_amdgcn_sched_barrier(0);
    bb = (bb + 1 == 3) ? 0 : bb + 1;
  }
#undef STAGE_T
  #pragma unroll
  for (int i = 0; i < 8; ++i)
    #pragma unroll
    for (int j = 0; j < 4; ++j) {
      const int col = n0 + cbase + j * 16 + lq;
      #pragma unroll
      for (int r = 0; r < 4; ++r)
        C[(size_t)(m0 + rbase + i * 16 + hi * 4 + r) * N + col] = acc[i][j][r];
    }
}

// ---- flash attention v7: CU-paired balance, single pass, 2 blk/CU ----
__global__ __launch_bounds__(256) void attn_kernel(
    const us* __restrict__ qb, const us* __restrict__ kb,
    const us* __restrict__ vb, us* __restrict__ ob) {
  const int head = blockIdx.y;
  const int qt = (head < 8) ? (int)blockIdx.x : 31 - (int)blockIdx.x;
  const int t = threadIdx.x, lane = t & 63, wave = t >> 6;
  const int hi = lane >> 4, lq = lane & 15;
  const int hd = head * HDIM;
  const int q0w = qt * 64 + wave * 16;
  __shared__ __align__(16) us Kl[2][64 * 64];   // XOR-swizzled
  __shared__ __align__(16) us Vl[2][64 * 72];   // V^T padded
  __shared__ __align__(16) us Pl[4][16][72];
  bf16x8 qf[2];
  {
    const us* qp = qb + (size_t)(q0w + lq) * EMB + hd + hi * 8;
    qf[0] = *(const bf16x8*)qp;
    qf[1] = *(const bf16x8*)(qp + 32);
    #pragma unroll
    for (int e = 0; e < 8; ++e) {
      qf[0][e] = (__bf16)((float)qf[0][e] * 0.125f);
      qf[1][e] = (__bf16)((float)qf[1][e] * 0.125f);
    }
  }
  f32x4 accO[4] = {};
  float m_run = -1e30f, l_run = 0.f;
  const int vr2 = (t >> 3) * 2, d8 = (t & 7) * 8;
  const int q_g = q0w + lq;

  {
    #pragma unroll
    for (int i = 0; i < 2; ++i) {
      const int c = wave * 64 + lane + i * 256;
      const int row = c >> 3, j = c & 7;
      const int colE = (j * 8) ^ ((row & 7) << 3);
      GLOAD_LDS16(kb + (size_t)(row) * EMB + hd + colE,
                  &Kl[0][0] + (wave * 64 + i * 256) * 8);
    }
    const us* vp = vb + (size_t)vr2 * EMB + hd + d8;
    uint4 vA = *(const uint4*)vp;
    uint4 vB = *(const uint4*)(vp + EMB);
    const unsigned* wa = (const unsigned*)&vA;
    const unsigned* wb = (const unsigned*)&vB;
    #pragma unroll
    for (int i = 0; i < 8; ++i) {
      unsigned lo = (i & 1) ? (wa[i >> 1] >> 16) : (wa[i >> 1] & 0xffffu);
      unsigned hw = (i & 1) ? (wb[i >> 1] >> 16) : (wb[i >> 1] & 0xffffu);
      *(unsigned*)(&Vl[0][0] + (d8 + i) * 72 + vr2) = lo | (hw << 16);
    }
  }
  __syncthreads();
  int cur = 0;
  for (int kt = 0; kt <= qt; ++kt) {
    uint4 vA, vB;
    if (kt < qt) {
      #pragma unroll
      for (int i = 0; i < 2; ++i) {
        const int c = wave * 64 + lane + i * 256;
        const int row = c >> 3, j = c & 7;
        const int colE = (j * 8) ^ ((row & 7) << 3);
        GLOAD_LDS16(kb + (size_t)((kt + 1) * 64 + row) * EMB + hd + colE,
                    &Kl[cur ^ 1][0] + (wave * 64 + i * 256) * 8);
      }
      const us* vp = vb + (size_t)((kt + 1) * 64 + vr2) * EMB + hd + d8;
      vA = *(const uint4*)vp;
      vB = *(const uint4*)(vp + EMB);
    }
    f32x4 sc[4] = {};
    #pragma unroll
    for (int ks = 0; ks < 2; ++ks) {
      #pragma unroll
      for (int fn = 0; fn < 4; ++fn) {
        const int rowk = fn * 16 + lq;
        const us* kp = &Kl[cur][0] + rowk * 64 + ((ks * 32 + hi * 8) ^ ((rowk & 7) << 3));
        sc[fn] = __builtin_amdgcn_mfma_f32_16x16x32_bf16(
            *(const bf16x8*)kp, qf[ks], sc[fn], 0, 0, 0);
      }
    }
    float pv[16];
    float pmax = -1e30f;
    if (kt == qt) {
      #pragma unroll
      for (int fn = 0; fn < 4; ++fn)
        #pragma unroll
        for (int r = 0; r < 4; ++r) {
          const int k_g = kt * 64 + fn * 16 + hi * 4 + r;
          float sv = sc[fn][r];
          if (k_g > q_g) sv = -1e30f;
          pv[fn * 4 + r] = sv;
          pmax = fmaxf(pmax, sv);
        }
    } else {
      #pragma unroll
      for (int fn = 0; fn < 4; ++fn)
        #pragma unroll
        for (int r = 0; r < 4; ++r) {
          float sv = sc[fn][r];
          pv[fn * 4 + r] = sv;
          pmax = fmaxf(pmax, sv);
        }
    }
    pmax = fmaxf(pmax, __shfl_xor(pmax, 16));
    pmax = fmaxf(pmax, __shfl_xor(pmax, 32));
    if (!__all(pmax <= m_run + 8.0f)) {
      const float mn = fmaxf(m_run, pmax);
      const float alpha = __expf(m_run - mn);
      m_run = mn;
      l_run *= alpha;
      float ar[4];
      #pragma unroll
      for (int r = 0; r < 4; ++r) ar[r] = __shfl(alpha, hi * 4 + r);
      #pragma unroll
      for (int df = 0; df < 4; ++df)
        #pragma unroll
        for (int r = 0; r < 4; ++r) accO[df][r] *= ar[r];
    }
    float rsum = 0.f;
    #pragma unroll
    for (int i = 0; i < 16; ++i) {
      float e = __expf(pv[i] - m_run);
      pv[i] = e;
      rsum += e;
    }
    rsum += __shfl_xor(rsum, 16);
    rsum += __shfl_xor(rsum, 32);
    l_run += rsum;
    #pragma unroll
    for (int fn = 0; fn < 4; ++fn) {
      ushort4 pk;
      pk.x = f2bf(pv[fn * 4 + 0]);
      pk.y = f2bf(pv[fn * 4 + 1]);
      pk.z = f2bf(pv[fn * 4 + 2]);
      pk.w = f2bf(pv[fn * 4 + 3]);
      *(ushort4*)&Pl[wave][lq][fn * 16 + hi * 4] = pk;
    }
    #pragma unroll
    for (int ks = 0; ks < 2; ++ks) {
      bf16x8 pf = *(const bf16x8*)&Pl[wave][lq][ks * 32 + hi * 8];
      #pragma unroll
      for (int df = 0; df < 4; ++df) {
        bf16x8 vf = *(const bf16x8*)(&Vl[cur][0] + (df * 16 + lq) * 72 + ks * 32 + hi * 8);
        accO[df] = __builtin_amdgcn_mfma_f32_16x16x32_bf16(pf, vf, accO[df], 0, 0, 0);
      }
    }
    if (kt < qt) {
      const unsigned* wa = (const unsigned*)&vA;
      const unsigned* wb = (const unsigned*)&vB;
      #pragma unroll
      for (int i = 0; i < 8; ++i) {
        unsigned lo = (i & 1) ? (wa[i >> 1] >> 16) : (wa[i >> 1] & 0xffffu);
        unsigned hw = (i & 1) ? (wb[i >> 1] >> 16) : (wb[i >> 1] & 0xffffu);
        *(unsigned*)(&Vl[cur ^ 1][0] + (d8 + i) * 72 + vr2) = lo | (hw << 16);
      }
    }
    __syncthreads();
    cur ^= 1;
  }
  float linv[4];
  #pragma unroll
  for (int r = 0; r < 4; ++r) linv[r] = 1.0f / __shfl(l_run, hi * 4 + r);
  #pragma unroll
  for (int r = 0; r < 4; ++r) {
    const int row = q0w + hi * 4 + r;
    #pragma unroll
    for (int df = 0; df < 4; ++df)
      ob[(size_t)row * EMB + hd + df * 16 + lq] = f2bf(accO[df][r] * linv[r]);
  }
}

// ---------------- host ----------------
extern "C" void kernel_launch(void* const* d_in, const int* in_sizes, int n_in,
                              void* d_out, int out_size, void* d_ws, size_t ws_size,
                              hipStream_t stream) {
  const int* tok = (const int*)d_in[0];
  const float* Wemb = (const float*)d_in[1];
  const float* Wpos = (const float*)d_in[2];
  const float* Wq = (const float*)d_in[3];
  const float* Wk = (const float*)d_in[4];
  const float* Wv = (const float*)d_in[5];
  const float* Wo = (const float*)d_in[6];
  const float* bo = (const float*)d_in[7];
  const float* ln1g = (const float*)d_in[8];
  const float* ln1b = (const float*)d_in[9];
  const float* ln2g = (const float*)d_in[10];
  const float* ln2b = (const float*)d_in[11];
  const float* W1 = (const float*)d_in[12];
  const float* b1 = (const float*)d_in[13];
  const float* W2 = (const float*)d_in[14];
  const float* b2 = (const float*)d_in[15];
  const float* lnfg = (const float*)d_in[16];
  const float* lnfb = (const float*)d_in[17];
  (void)in_sizes; (void)n_in; (void)out_size;

  const size_t MB = 1u << 20;
  char* ws = (char*)d_ws;
  float* x = (float*)ws;                       // [0, 8MB)
  us* h  = (us*)(ws + 8 * MB);
  us* qb = (us*)(ws + 12 * MB);
  us* kb = (us*)(ws + 16 * MB);
  us* vb = (us*)(ws + 20 * MB);
  us* ob = (us*)(ws + 24 * MB);
  us* fb = (us*)(ws + 12 * MB);                // alias qb..ob (phase-disjoint)
  us* cWq = (us*)(ws + 28 * MB);
  us* cWk = (us*)(ws + 40 * MB);
  us* cWv = (us*)(ws + 52 * MB);
  us* cWo = (us*)(ws + 64 * MB);
  us* cW1 = (us*)(ws + 76 * MB);
  us* cW2 = (us*)(ws + 124 * MB);
  us* cWemb = (us*)(ws + 172 * MB);            // ends ~234.5 MB
  float* pbuf = (float*)(ws + 236 * MB);
  const size_t need = 236 * MB + 32 * MB;
  if (ws_size < need) {
    embed_kernel<<<dim3(S_LEN), 256, 0, stream>>>(tok, Wemb, Wpos, x);
    return;
  }

  embed_kernel<<<dim3(S_LEN), 256, 0, stream>>>(tok, Wemb, Wpos, x);

  const long nE2 = (long)NLAYER * EMB * EMB;
  const long nF  = (long)NLAYER * FFDIM * EMB;
  const long nV  = (long)VOCAB * EMB;
  cvt_bf16_kernel<<<(int)(nE2 / 2048), 256, 0, stream>>>(Wq, cWq, nE2);
  cvt_bf16_kernel<<<(int)(nE2 / 2048), 256, 0, stream>>>(Wk, cWk, nE2);
  cvt_bf16_kernel<<<(int)(nE2 / 2048), 256, 0, stream>>>(Wv, cWv, nE2);
  cvt_bf16_kernel<<<(int)(nE2 / 2048), 256, 0, stream>>>(Wo, cWo, nE2);
  cvt_bf16_kernel<<<(int)(nF / 2048), 256, 0, stream>>>(W1, cW1, nF);
  cvt_bf16_kernel<<<(int)(nF / 2048), 256, 0, stream>>>(W2, cW2, nF);
  cvt_bf16_kernel<<<(int)(nV / 2048), 256, 0, stream>>>(Wemb, cWemb, nV);

  ln_kernel<<<S_LEN, 256, 0, stream>>>(x, ln1g, ln1b, h);  // layer-0 ln1
  for (int l = 0; l < NLAYER; ++l) {
    const size_t wofs = (size_t)l * EMB * EMB;
    const size_t fofs = (size_t)l * FFDIM * EMB;
    gemm_r128<0, 0, 1><<<dim3(16, 8, 3), 256, 0, stream>>>(
        h, cWq + wofs, cWk + wofs, cWv + wofs, nullptr,
        qb, kb, vb, S_LEN, EMB, EMB);
    attn_kernel<<<dim3(32, NHEAD), 256, 0, stream>>>(qb, kb, vb, ob);
    gemm_rsk<<<dim3(16, 8, 2), 256, 0, stream>>>(
        ob, cWo + wofs, pbuf, S_LEN, EMB, EMB, EMB / 2);
    reduce_ln_kernel<2><<<S_LEN, 256, 0, stream>>>(
        x, pbuf, bo + l * EMB, ln2g + l * EMB, ln2b + l * EMB, h);
    gemm_r128<1, 1, 1><<<dim3(16, 32, 1), 256, 0, stream>>>(
        h, cW1 + fofs, nullptr, nullptr, b1 + l * FFDIM,
        fb, nullptr, nullptr, S_LEN, FFDIM, EMB);
    gemm_rsk<<<dim3(16, 8, 4), 256, 0, stream>>>(
        fb, cW2 + fofs, pbuf, S_LEN, EMB, FFDIM, FFDIM / 4);
    if (l < NLAYER - 1)
      reduce_ln_kernel<4><<<S_LEN, 256, 0, stream>>>(
          x, pbuf, b2 + l * EMB, ln1g + (l + 1) * EMB, ln1b + (l + 1) * EMB, h);
    else
      reduce_ln_kernel<4><<<S_LEN, 256, 0, stream>>>(
          x, pbuf, b2 + l * EMB, lnfg, lnfb, h);
  }
  gemm_v8p<<<dim3(8, 125), 512, 0, stream>>>(
      h, cWemb, (float*)d_out, S_LEN, VOCAB, EMB);
}